// Round 1
// baseline (111.616 us; speedup 1.0000x reference)
//
#include <hip/hip_runtime.h>

// FuzzySystemLayer, single fused kernel. B=262144, C=256, D=64, O=8 (fp32).
// GEMM1 in fp16 (32x32x16_f16): acc[c_row, b_col] = log2-domain exponent
//   e = (2*x.c)*k - k*x^2 - k*c^2,  k = log2(e)/(2 w^2)
//   5 K-blocks: 4x [A=fp16(2k*c) x B=fp16(x)] + 1 affine block (hi/lo fp16
//   splits of k, x^2, k*c^2; pair error ~2^-22).
// GEMM2 in bf16 (memb spans 2^-40..2^-200: fp16 would flush to zero).
//   out2[o,b] = W'^T @ memb, W' row 8 = ones -> normalizer.
// Cluster rows permuted by swap23 so exp2(acc) registers ARE GEMM2 B-fragments.
// R2: no local array indexed by runtime var (scratch demotion).
// R4: fragment loads from L2 were the latency wall -> LDS staging.
// R6: x B-slice is h-dependent: float4 idx 4*kd + 2*h (+1).
// R7/R9: phase-aligned load->barrier->compute ADDS phases (~28 us kernel).
// R8: 4-deep register pipelining spilled (2xRaw8+2xXF live -> 100 MB scratch).
// R10: 1-deep prefetch, 2 sequential tile passes. ~110.5 us bench.
// R11 (this round): FUSE the two b-tiles into ONE t-loop. Each A/W fragment
//   ds_read feeds both tiles' MFMAs: per-wave ds_read_b128 224->112, loop
//   overhead halved, and tile1's GEMM1 MFMAs overlap tile0's exp2 VALU chain
//   within the wave. Both Raw8 loads issue BEFORE prep so the wave pays one
//   HBM latency total (prep's center/W waits drain the raw loads too).
//   Live set in loop: xf0+xf1(40) + acc2x2(32) + A(20) + w(8) + acc(16)
//   + transients; #pragma unroll 1 keeps it under the 128-VGPR / 4-wave cap.

#define NB 262144
#define NC 256
#define ND 64
#define NO 8

typedef __attribute__((ext_vector_type(8))) short short8;
typedef __attribute__((ext_vector_type(8))) _Float16 half8;
typedef __attribute__((ext_vector_type(16))) float floatx16;

// LDS layout in shorts:
//   A (fp16):  ((t*5 + idx)*64 + lane)*8 + j   idx 0..3 = 2k*c, idx 4 = affine
//   W (bf16):  20480 + (k2*64 + lane)*8 + j    k2 = 0..15
#define WOFF 20480
#define WS_SHORTS 28672  // 56 KB

__device__ inline unsigned short f2bf(float f) {
    unsigned u = __builtin_bit_cast(unsigned, f);
    u = u + 0x7FFFu + ((u >> 16) & 1u);
    return (unsigned short)(u >> 16);
}

struct Raw8 { float4 r0, r1, r2, r3, r4, r5, r6, r7; };
struct XF { half8 k0, k1, k2, k3, f12; };

__device__ __forceinline__ Raw8 load_x(const float* __restrict__ xrow, int h) {
    const float4* xp = (const float4*)xrow;
    Raw8 r;
    r.r0 = xp[0 + 2 * h];  r.r1 = xp[1 + 2 * h];
    r.r2 = xp[4 + 2 * h];  r.r3 = xp[5 + 2 * h];
    r.r4 = xp[8 + 2 * h];  r.r5 = xp[9 + 2 * h];
    r.r6 = xp[12 + 2 * h]; r.r7 = xp[13 + 2 * h];
    return r;
}

__device__ __forceinline__ half8 cvt8(float4 a, float4 b, float& part) {
    float v[8] = {a.x, a.y, a.z, a.w, b.x, b.y, b.z, b.w};
    half8 hh;
#pragma unroll
    for (int j = 0; j < 8; ++j) {
        part = fmaf(v[j], v[j], part);
        hh[j] = (_Float16)v[j];
    }
    return hh;
}

__device__ __forceinline__ XF convert_x(const Raw8& r, int h) {
    float part = 0.0f;
    XF f;
    f.k0 = cvt8(r.r0, r.r1, part);
    f.k1 = cvt8(r.r2, r.r3, part);
    f.k2 = cvt8(r.r4, r.r5, part);
    f.k3 = cvt8(r.r6, r.r7, part);
    float xsq = part + __shfl_xor(part, 32, 64);
    float sh = (float)(_Float16)xsq;
    float sl = xsq - sh;
    half8 ff;
#pragma unroll
    for (int j = 0; j < 8; ++j) ff[j] = (_Float16)0.0f;
    if (h == 0) {
        ff[0] = (_Float16)sh;
        ff[1] = (_Float16)sl;
        ff[2] = (_Float16)sh;
        ff[3] = (_Float16)1.0f;
        ff[4] = (_Float16)1.0f;
    }
    f.f12 = ff;
    return f;
}

// exp2 of 16 accs -> 2 packed bf16x8 GEMM2 B-fragments (RTZ via v_perm).
__device__ __forceinline__ void exp_pack(const floatx16& acc, short8& pf0, short8& pf1) {
    unsigned q[8];
#pragma unroll
    for (int i = 0; i < 8; ++i) {
        unsigned lo = __builtin_bit_cast(unsigned, __builtin_amdgcn_exp2f(acc[2 * i]));
        unsigned hi = __builtin_bit_cast(unsigned, __builtin_amdgcn_exp2f(acc[2 * i + 1]));
        q[i] = __builtin_amdgcn_perm(hi, lo, 0x07060302u);
    }
    uint4 q0; q0.x = q[0]; q0.y = q[1]; q0.z = q[2]; q0.w = q[3];
    uint4 q1; q1.x = q[4]; q1.y = q[5]; q1.z = q[6]; q1.w = q[7];
    pf0 = __builtin_bit_cast(short8, q0);
    pf1 = __builtin_bit_cast(short8, q1);
}

__device__ __forceinline__ void finish(const floatx16& acc2, int h, float* __restrict__ outp) {
    float S = acc2[4];  // row 8 (normalizer) lives at h==0, reg 4
    float Sp = __shfl_xor(S, 32, 64);
    if (h) S = Sp;
    float inv = 1.0f / S;
    float4 r;
    r.x = acc2[0] * inv;
    r.y = acc2[1] * inv;
    r.z = acc2[2] * inv;
    r.w = acc2[3] * inv;
    ((float4*)outp)[h] = r;  // h=0: o=0..3, h=1: o=4..7
}

// Fused two-tile t-loop: one A/W fragment read feeds both tiles.
// unroll 1 deliberately: transients stay at ONE t-step's worth (R8/R10 lesson).
__device__ __forceinline__ void compute_pair(const short* lds_s, int lane, int h,
                                             const XF& xf0, const XF& xf1,
                                             float* __restrict__ out0,
                                             float* __restrict__ out1) {
    floatx16 accA, accB;
#pragma unroll
    for (int i = 0; i < 16; ++i) { accA[i] = 0.0f; accB[i] = 0.0f; }

#pragma unroll 1
    for (int t = 0; t < 8; ++t) {
        const half8 A0 = *(const half8*)&lds_s[((t * 5 + 0) * 64 + lane) * 8];
        const half8 A1 = *(const half8*)&lds_s[((t * 5 + 1) * 64 + lane) * 8];
        const half8 A2 = *(const half8*)&lds_s[((t * 5 + 2) * 64 + lane) * 8];
        const half8 A3 = *(const half8*)&lds_s[((t * 5 + 3) * 64 + lane) * 8];
        const half8 C12 = *(const half8*)&lds_s[((t * 5 + 4) * 64 + lane) * 8];
        const short8 w0 = *(const short8*)&lds_s[WOFF + ((2 * t + 0) * 64 + lane) * 8];
        const short8 w1 = *(const short8*)&lds_s[WOFF + ((2 * t + 1) * 64 + lane) * 8];

        // ---- tile 0 ----
        {
            floatx16 acc;
#pragma unroll
            for (int i = 0; i < 16; ++i) acc[i] = 0.0f;
            acc = __builtin_amdgcn_mfma_f32_32x32x16_f16(A0, xf0.k0, acc, 0, 0, 0);
            acc = __builtin_amdgcn_mfma_f32_32x32x16_f16(A1, xf0.k1, acc, 0, 0, 0);
            acc = __builtin_amdgcn_mfma_f32_32x32x16_f16(A2, xf0.k2, acc, 0, 0, 0);
            acc = __builtin_amdgcn_mfma_f32_32x32x16_f16(A3, xf0.k3, acc, 0, 0, 0);
            acc = __builtin_amdgcn_mfma_f32_32x32x16_f16(C12, xf0.f12, acc, 0, 0, 0);
            short8 pf0, pf1;
            exp_pack(acc, pf0, pf1);
            accA = __builtin_amdgcn_mfma_f32_32x32x16_bf16(w0, pf0, accA, 0, 0, 0);
            accA = __builtin_amdgcn_mfma_f32_32x32x16_bf16(w1, pf1, accA, 0, 0, 0);
        }

        // ---- tile 1 (A/C12/w still live; GEMM1 here overlaps tile0's exp2) ----
        {
            floatx16 acc;
#pragma unroll
            for (int i = 0; i < 16; ++i) acc[i] = 0.0f;
            acc = __builtin_amdgcn_mfma_f32_32x32x16_f16(A0, xf1.k0, acc, 0, 0, 0);
            acc = __builtin_amdgcn_mfma_f32_32x32x16_f16(A1, xf1.k1, acc, 0, 0, 0);
            acc = __builtin_amdgcn_mfma_f32_32x32x16_f16(A2, xf1.k2, acc, 0, 0, 0);
            acc = __builtin_amdgcn_mfma_f32_32x32x16_f16(A3, xf1.k3, acc, 0, 0, 0);
            acc = __builtin_amdgcn_mfma_f32_32x32x16_f16(C12, xf1.f12, acc, 0, 0, 0);
            short8 pf0, pf1;
            exp_pack(acc, pf0, pf1);
            accB = __builtin_amdgcn_mfma_f32_32x32x16_bf16(w0, pf0, accB, 0, 0, 0);
            accB = __builtin_amdgcn_mfma_f32_32x32x16_bf16(w1, pf1, accB, 0, 0, 0);
        }
    }

    finish(accA, h, out0);
    finish(accB, h, out1);
}

__global__ __launch_bounds__(512, 4) void fuzzy_main(
    const float* __restrict__ x,
    const float* __restrict__ centers,
    const float* __restrict__ widths,
    const float* __restrict__ W,
    float* __restrict__ out) {
    __shared__ short lds_s[WS_SHORTS];

    const int tid = threadIdx.x;
    const int wave = tid >> 6;
    const int lane = tid & 63;
    const int col = lane & 31;
    const int h = lane >> 5;
    const int bbase = (blockIdx.x * 8 + wave) * 64;  // 64 b-columns per wave
    const int b0 = bbase + col;
    const int b1 = bbase + 32 + col;

    // ---- both tiles' x loads first: one exposed HBM latency per wave ----
    Raw8 raw0 = load_x(x + (size_t)b0 * ND, h);
    Raw8 raw1 = load_x(x + (size_t)b1 * ND, h);

    // ---- fused prep: wave t builds tile t's fragments into LDS ----
    {
        const int t = wave;
        // cluster at GEMM1 row `col` of tile t: swap bits 2<->3 (self-inverse)
        const int c = 32 * t + ((col & 19) | ((col & 4) << 1) | ((col & 8) >> 1));
        const float* cr = centers + c * ND;
        float vv[4][8];
        float part = 0.0f;
#pragma unroll
        for (int kd = 0; kd < 4; ++kd) {
            const float4* p = (const float4*)(cr + kd * 16 + h * 8);
            float4 a0 = p[0], a1 = p[1];
            vv[kd][0] = a0.x; vv[kd][1] = a0.y; vv[kd][2] = a0.z; vv[kd][3] = a0.w;
            vv[kd][4] = a1.x; vv[kd][5] = a1.y; vv[kd][6] = a1.z; vv[kd][7] = a1.w;
#pragma unroll
            for (int j = 0; j < 8; ++j) part = fmaf(vv[kd][j], vv[kd][j], part);
        }
        float csq = part + __shfl_xor(part, 32, 64);
        float w = widths[c];
        float kk = 1.4426950408889634f / (2.0f * w * w);  // log2(e)/(2w^2)

#pragma unroll
        for (int kd = 0; kd < 4; ++kd) {
            half8 ah;
#pragma unroll
            for (int j = 0; j < 8; ++j) ah[j] = (_Float16)(2.0f * kk * vv[kd][j]);
            *(half8*)&lds_s[((t * 5 + kd) * 64 + lane) * 8] = ah;
        }
        // affine block (idx 4), nonzero only on h==0:
        // A = [-k_h, -k_h, -k_l, -(kc^2)_h, -(kc^2)_l, 0,0,0]
        // pairs B = [x2_h, x2_l, x2_h, 1, 1, 0,0,0]
        half8 av;
#pragma unroll
        for (int j = 0; j < 8; ++j) av[j] = (_Float16)0.0f;
        if (h == 0) {
            float kh = (float)(_Float16)kk;
            float kl = kk - kh;
            float Bc = csq * kk;
            float Bh = (float)(_Float16)Bc;
            float Bl = Bc - Bh;
            av[0] = (_Float16)(-kh);
            av[1] = (_Float16)(-kh);
            av[2] = (_Float16)(-kl);
            av[3] = (_Float16)(-Bh);
            av[4] = (_Float16)(-Bl);
        }
        *(half8*)&lds_s[((t * 5 + 4) * 64 + lane) * 8] = av;

        // W' fragments (bf16): A[m=o][k=c]; o=col; row 8 = ones (normalizer)
#pragma unroll
        for (int q = 0; q < 2; ++q) {
            int k2 = 2 * t + q;
            short8 wf;
#pragma unroll
            for (int j = 0; j < 8; ++j) {
                int c2 = k2 * 16 + h * 8 + j;  // natural order (perm self-inverts)
                float val = (col < NO) ? W[c2 * NO + col] : (col == 8 ? 1.0f : 0.0f);
                wf[j] = (short)f2bf(val);
            }
            *(short8*)&lds_s[WOFF + (k2 * 64 + lane) * 8] = wf;
        }
    }

    // converts before the barrier: raw data already in flight since kernel start
    XF xf0 = convert_x(raw0, h);  // raw0 dies here
    XF xf1 = convert_x(raw1, h);  // raw1 dies here
    __syncthreads();

    compute_pair(lds_s, lane, h, xf0, xf1,
                 out + (size_t)b0 * NO, out + (size_t)b1 * NO);
}

extern "C" void kernel_launch(void* const* d_in, const int* in_sizes, int n_in,
                              void* d_out, int out_size, void* d_ws, size_t ws_size,
                              hipStream_t stream) {
    const float* x       = (const float*)d_in[0];  // [B, D]
    const float* centers = (const float*)d_in[1];  // [C, D]
    const float* widths  = (const float*)d_in[2];  // [C]
    const float* W       = (const float*)d_in[3];  // [C, O]
    float* out = (float*)d_out;
    (void)d_ws; (void)ws_size;

    // 512 blocks x 512 threads, all resident (2 blocks/CU); each wave: 64
    // b-columns fused into one t-loop pass over the shared A/W fragments.
    fuzzy_main<<<NB / 512, 512, 0, stream>>>(x, centers, widths, W, out);
}